// Round 2
// baseline (599.842 us; speedup 1.0000x reference)
//
#include <hip/hip_runtime.h>

#define DD 160
#define HH 160
#define WW 160
#define NVOX (DD * HH * WW)

// Identity-grid + align_corners=true: pixel coord = idx + v * 0.5*(dim-1)
#define HALF_EXTENT 79.5f  // 0.5 * (160 - 1)

// ---------- padded-path kernels (float4 per voxel) ----------

// pack: vel * s -> padded float4 buffer
__global__ __launch_bounds__(256) void gs_pack(const float* __restrict__ in,
                                               float4* __restrict__ out, float s) {
    int i = blockIdx.x * blockDim.x + threadIdx.x;
    if (i < NVOX) {
        float4 v;
        v.x = in[i * 3 + 0] * s;
        v.y = in[i * 3 + 1] * s;
        v.z = in[i * 3 + 2] * s;
        v.w = 0.0f;
        out[i] = v;
    }
}

// one step on padded layout; optionally write packed [*,3] (final step -> d_out)
template <bool WRITE_PACKED>
__global__ __launch_bounds__(256) void gs_step_pad(const float4* __restrict__ vin,
                                                   float4* __restrict__ vout_pad,
                                                   float* __restrict__ vout_packed) {
    int tid = blockIdx.x * blockDim.x + threadIdx.x;
    if (tid >= NVOX) return;

    int x = tid % WW;
    int t = tid / WW;
    int y = t % HH;
    int z = t / HH;

    float4 v = vin[tid];

    float fx = (float)x + v.x * HALF_EXTENT;
    float fy = (float)y + v.y * HALF_EXTENT;
    float fz = (float)z + v.z * HALF_EXTENT;

    float x0f = floorf(fx), y0f = floorf(fy), z0f = floorf(fz);
    float wx = fx - x0f, wy = fy - y0f, wz = fz - z0f;
    int x0 = (int)x0f, y0 = (int)y0f, z0 = (int)z0f;

    float acc0 = 0.0f, acc1 = 0.0f, acc2 = 0.0f;

#pragma unroll
    for (int dz = 0; dz < 2; ++dz) {
        int zi = z0 + dz;
        float wzz = dz ? wz : (1.0f - wz);
        bool zok = (zi >= 0) & (zi < DD);
#pragma unroll
        for (int dy = 0; dy < 2; ++dy) {
            int yi = y0 + dy;
            float wyy = dy ? wy : (1.0f - wy);
            bool yok = (yi >= 0) & (yi < HH);
#pragma unroll
            for (int dx = 0; dx < 2; ++dx) {
                int xi = x0 + dx;
                float wxx = dx ? wx : (1.0f - wx);
                bool xok = (xi >= 0) & (xi < WW);
                if (zok & yok & xok) {
                    float4 p = vin[(size_t)(zi * HH + yi) * WW + xi];
                    float w = wzz * wyy * wxx;
                    acc0 = fmaf(w, p.x, acc0);
                    acc1 = fmaf(w, p.y, acc1);
                    acc2 = fmaf(w, p.z, acc2);
                }
            }
        }
    }

    float r0 = v.x + acc0, r1 = v.y + acc1, r2 = v.z + acc2;

    if (WRITE_PACKED) {
        int base = tid * 3;
        vout_packed[base + 0] = r0;
        vout_packed[base + 1] = r1;
        vout_packed[base + 2] = r2;
    } else {
        float4 r;
        r.x = r0; r.y = r1; r.z = r2; r.w = 0.0f;
        vout_pad[tid] = r;
    }
}

// ---------- fallback-path kernels (packed [*,3], analytic grid) ----------

__global__ __launch_bounds__(256) void gs_init_scale(const float* __restrict__ in,
                                                     float* __restrict__ out,
                                                     int n4, float s) {
    int i = blockIdx.x * blockDim.x + threadIdx.x;
    if (i < n4) {
        float4 v = reinterpret_cast<const float4*>(in)[i];
        v.x *= s; v.y *= s; v.z *= s; v.w *= s;
        reinterpret_cast<float4*>(out)[i] = v;
    }
}

__global__ __launch_bounds__(256) void gs_step_packed(const float* __restrict__ vin,
                                                      float* __restrict__ vout) {
    int tid = blockIdx.x * blockDim.x + threadIdx.x;
    if (tid >= NVOX) return;

    int x = tid % WW;
    int t = tid / WW;
    int y = t % HH;
    int z = t / HH;

    int base = tid * 3;
    float vx = vin[base + 0];
    float vy = vin[base + 1];
    float vz = vin[base + 2];

    float fx = (float)x + vx * HALF_EXTENT;
    float fy = (float)y + vy * HALF_EXTENT;
    float fz = (float)z + vz * HALF_EXTENT;

    float x0f = floorf(fx), y0f = floorf(fy), z0f = floorf(fz);
    float wx = fx - x0f, wy = fy - y0f, wz = fz - z0f;
    int x0 = (int)x0f, y0 = (int)y0f, z0 = (int)z0f;

    float acc0 = 0.0f, acc1 = 0.0f, acc2 = 0.0f;

#pragma unroll
    for (int dz = 0; dz < 2; ++dz) {
        int zi = z0 + dz;
        float wzz = dz ? wz : (1.0f - wz);
        bool zok = (zi >= 0) & (zi < DD);
#pragma unroll
        for (int dy = 0; dy < 2; ++dy) {
            int yi = y0 + dy;
            float wyy = dy ? wy : (1.0f - wy);
            bool yok = (yi >= 0) & (yi < HH);
#pragma unroll
            for (int dx = 0; dx < 2; ++dx) {
                int xi = x0 + dx;
                float wxx = dx ? wx : (1.0f - wx);
                bool xok = (xi >= 0) & (xi < WW);
                if (zok & yok & xok) {
                    const float* p = vin + (size_t)((zi * HH + yi) * WW + xi) * 3;
                    float w = wzz * wyy * wxx;
                    acc0 = fmaf(w, p[0], acc0);
                    acc1 = fmaf(w, p[1], acc1);
                    acc2 = fmaf(w, p[2], acc2);
                }
            }
        }
    }

    vout[base + 0] = vx + acc0;
    vout[base + 1] = vy + acc1;
    vout[base + 2] = vz + acc2;
}

extern "C" void kernel_launch(void* const* d_in, const int* in_sizes, int n_in,
                              void* d_out, int out_size, void* d_ws, size_t ws_size,
                              hipStream_t stream) {
    const float* vel = (const float*)d_in[0];
    float* out = (float*)d_out;

    const float scale = 1.0f / 64.0f;  // 1 / 2^6
    dim3 blk(256);
    dim3 grd((NVOX + 255) / 256);

    const size_t pad_buf_bytes = (size_t)NVOX * 4 * sizeof(float);  // 65.536 MB

    if (ws_size >= 2 * pad_buf_bytes) {
        // padded fast path
        float4* A = (float4*)d_ws;
        float4* B = (float4*)((char*)d_ws + pad_buf_bytes);

        gs_pack<<<grd, blk, 0, stream>>>(vel, A, scale);

        // steps 1..5 padded ping-pong: A->B->A->B->A->B
        float4* src = A;
        float4* dst = B;
        for (int i = 0; i < 5; ++i) {
            gs_step_pad<false><<<grd, blk, 0, stream>>>(src, dst, nullptr);
            float4* tmp = src; src = dst; dst = tmp;
        }
        // step 6: padded -> packed d_out
        gs_step_pad<true><<<grd, blk, 0, stream>>>(src, nullptr, out);
    } else {
        // fallback: packed layout ping-pong (round-1 structure, analytic grid)
        float* ws = (float*)d_ws;
        const int n4 = NVOX * 3 / 4;
        dim3 grd_init((n4 + 255) / 256);

        gs_init_scale<<<grd_init, blk, 0, stream>>>(vel, out, n4, scale);

        float* src = out;
        float* dst = ws;
        for (int i = 0; i < 6; ++i) {
            gs_step_packed<<<grd, blk, 0, stream>>>(src, dst);
            float* tmp = src; src = dst; dst = tmp;
        }
    }
}

// Round 3
// 504.239 us; speedup vs baseline: 1.1896x; 1.1896x over previous
//
#include <hip/hip_runtime.h>

#define DD 160
#define HH 160
#define WW 160
#define NVOX (DD * HH * WW)
#define NBLOCK (NVOX / 256)        // 16000, divisible by 8
#define HALF_EXTENT 79.5f          // 0.5 * (160 - 1), identity grid analytic

// One step on packed [D,H,W,3] fp32 layout, analytic identity grid.
// SCALE_SRC: read raw velocity and fold the 1/2^n scale in (fused first step).
// vout written with non-temporal stores (never re-read within this kernel).
template <bool SCALE_SRC>
__global__ __launch_bounds__(256) void gs_step(const float* __restrict__ vin,
                                               float* __restrict__ vout,
                                               float s) {
    // XCD-aware swizzle: 16000 blocks -> each of 8 XCDs owns a contiguous
    // 2000-block chunk == a contiguous 20-slice z-slab (L2 gather locality).
    int bid = blockIdx.x;
    int swz = (bid & 7) * (NBLOCK >> 3) + (bid >> 3);
    int tid = swz * 256 + (int)threadIdx.x;

    int x = tid % WW;
    int t = tid / WW;
    int y = t % HH;
    int z = t / HH;

    int base = tid * 3;
    float vx = vin[base + 0];
    float vy = vin[base + 1];
    float vz = vin[base + 2];
    if (SCALE_SRC) { vx *= s; vy *= s; vz *= s; }

    float fx = (float)x + vx * HALF_EXTENT;
    float fy = (float)y + vy * HALF_EXTENT;
    float fz = (float)z + vz * HALF_EXTENT;

    float x0f = floorf(fx), y0f = floorf(fy), z0f = floorf(fz);
    float wx = fx - x0f, wy = fy - y0f, wz = fz - z0f;
    int x0 = (int)x0f, y0 = (int)y0f, z0 = (int)z0f;

    float acc0 = 0.0f, acc1 = 0.0f, acc2 = 0.0f;

#pragma unroll
    for (int dz = 0; dz < 2; ++dz) {
        int zi = z0 + dz;
        float wzz = dz ? wz : (1.0f - wz);
        bool zok = (zi >= 0) & (zi < DD);
#pragma unroll
        for (int dy = 0; dy < 2; ++dy) {
            int yi = y0 + dy;
            float wyy = dy ? wy : (1.0f - wy);
            bool yok = (yi >= 0) & (yi < HH);
#pragma unroll
            for (int dx = 0; dx < 2; ++dx) {
                int xi = x0 + dx;
                float wxx = dx ? wx : (1.0f - wx);
                bool xok = (xi >= 0) & (xi < WW);
                if (zok & yok & xok) {
                    const float* p = vin + (size_t)((zi * HH + yi) * WW + xi) * 3;
                    float w = wzz * wyy * wxx;
                    acc0 = fmaf(w, p[0], acc0);
                    acc1 = fmaf(w, p[1], acc1);
                    acc2 = fmaf(w, p[2], acc2);
                }
            }
        }
    }

    if (SCALE_SRC) { acc0 *= s; acc1 *= s; acc2 *= s; }

    __builtin_nontemporal_store(vx + acc0, &vout[base + 0]);
    __builtin_nontemporal_store(vy + acc1, &vout[base + 1]);
    __builtin_nontemporal_store(vz + acc2, &vout[base + 2]);
}

// fallback init (only used if workspace is too small for two packed buffers)
__global__ __launch_bounds__(256) void gs_init_scale(const float* __restrict__ in,
                                                     float* __restrict__ out,
                                                     int n4, float s) {
    int i = blockIdx.x * blockDim.x + threadIdx.x;
    if (i < n4) {
        float4 v = reinterpret_cast<const float4*>(in)[i];
        v.x *= s; v.y *= s; v.z *= s; v.w *= s;
        reinterpret_cast<float4*>(out)[i] = v;
    }
}

extern "C" void kernel_launch(void* const* d_in, const int* in_sizes, int n_in,
                              void* d_out, int out_size, void* d_ws, size_t ws_size,
                              hipStream_t stream) {
    const float* vel = (const float*)d_in[0];
    float* out = (float*)d_out;

    const float scale = 1.0f / 64.0f;  // 1 / 2^6
    dim3 blk(256);
    dim3 grd(NBLOCK);

    const size_t buf_bytes = (size_t)NVOX * 3 * sizeof(float);  // 49.152 MB

    if (ws_size >= 2 * buf_bytes) {
        float* A = (float*)d_ws;
        float* B = (float*)((char*)d_ws + buf_bytes);

        // step 1 fused with the 1/64 scale: vel -> A
        gs_step<true><<<grd, blk, 0, stream>>>(vel, A, scale);
        // steps 2..5 ping-pong A->B->A->B->A
        gs_step<false><<<grd, blk, 0, stream>>>(A, B, scale);
        gs_step<false><<<grd, blk, 0, stream>>>(B, A, scale);
        gs_step<false><<<grd, blk, 0, stream>>>(A, B, scale);
        gs_step<false><<<grd, blk, 0, stream>>>(B, A, scale);
        // step 6: A -> d_out
        gs_step<false><<<grd, blk, 0, stream>>>(A, out, scale);
    } else {
        // fallback: init into out, 6 steps out<->ws, even count ends in out
        float* ws = (float*)d_ws;
        const int n4 = NVOX * 3 / 4;
        dim3 grd_init((n4 + 255) / 256);

        gs_init_scale<<<grd_init, blk, 0, stream>>>(vel, out, n4, scale);

        float* src = out;
        float* dst = ws;
        for (int i = 0; i < 6; ++i) {
            gs_step<false><<<grd, blk, 0, stream>>>(src, dst, scale);
            float* tmp = src; src = dst; dst = tmp;
        }
    }
}

// Round 4
// 340.488 us; speedup vs baseline: 1.7617x; 1.4809x over previous
//
#include <hip/hip_runtime.h>

#define DD 160
#define HH 160
#define WW 160
#define NVOX (DD * HH * WW)
#define NBLOCK (NVOX / 256)        // 16000, divisible by 8
#define HALF_EXTENT 79.5f          // 0.5 * (160 - 1), identity grid analytic

// One scaling-and-squaring step on packed [D,H,W,3] fp32, analytic identity
// grid, zeros padding. Branchless trilinear gather: validity folded into
// per-axis weights, loads from clamped addresses issued unconditionally so
// all 24 gather dwords are in flight under one waitcnt (MLP ~27/wave).
// SCALE_SRC: fold the 1/2^n scale into the first step (reads raw velocity).
// NT_OUT:   non-temporal stores (final step only; intermediates are re-read).
template <bool SCALE_SRC, bool NT_OUT>
__global__ __launch_bounds__(256) void gs_step(const float* __restrict__ vin,
                                               float* __restrict__ vout,
                                               float s) {
    // XCD-aware swizzle: each of 8 XCDs owns a contiguous 20-z-slice slab.
    int bid = blockIdx.x;
    int swz = (bid & 7) * (NBLOCK >> 3) + (bid >> 3);
    int tid = swz * 256 + (int)threadIdx.x;

    int x = tid % WW;
    int t = tid / WW;
    int y = t % HH;
    int z = t / HH;

    int base = tid * 3;
    float vx = vin[base + 0];
    float vy = vin[base + 1];
    float vz = vin[base + 2];
    if (SCALE_SRC) { vx *= s; vy *= s; vz *= s; }

    float fx = fmaf(vx, HALF_EXTENT, (float)x);
    float fy = fmaf(vy, HALF_EXTENT, (float)y);
    float fz = fmaf(vz, HALF_EXTENT, (float)z);

    float x0f = floorf(fx), y0f = floorf(fy), z0f = floorf(fz);
    float wx = fx - x0f, wy = fy - y0f, wz = fz - z0f;
    int x0 = (int)x0f, y0 = (int)y0f, z0 = (int)z0f;
    int x1 = x0 + 1, y1 = y0 + 1, z1 = z0 + 1;

    // per-axis weights with zeros-padding validity folded in
    float ax0 = (x0 >= 0 && x0 < WW) ? (1.0f - wx) : 0.0f;
    float ax1 = (x1 >= 0 && x1 < WW) ? wx : 0.0f;
    float ay0 = (y0 >= 0 && y0 < HH) ? (1.0f - wy) : 0.0f;
    float ay1 = (y1 >= 0 && y1 < HH) ? wy : 0.0f;
    float az0 = (z0 >= 0 && z0 < DD) ? (1.0f - wz) : 0.0f;
    float az1 = (z1 >= 0 && z1 < DD) ? wz : 0.0f;

    // clamped address components (always-safe loads)
    int x0c = min(max(x0, 0), WW - 1), x1c = min(max(x1, 0), WW - 1);
    int y0c = min(max(y0, 0), HH - 1), y1c = min(max(y1, 0), HH - 1);
    int z0c = min(max(z0, 0), DD - 1), z1c = min(max(z1, 0), DD - 1);

    int zs0 = z0c * (HH * WW), zs1 = z1c * (HH * WW);
    int ys0 = y0c * WW,        ys1 = y1c * WW;

    const float* p000 = vin + (size_t)(zs0 + ys0 + x0c) * 3;
    const float* p001 = vin + (size_t)(zs0 + ys0 + x1c) * 3;
    const float* p010 = vin + (size_t)(zs0 + ys1 + x0c) * 3;
    const float* p011 = vin + (size_t)(zs0 + ys1 + x1c) * 3;
    const float* p100 = vin + (size_t)(zs1 + ys0 + x0c) * 3;
    const float* p101 = vin + (size_t)(zs1 + ys0 + x1c) * 3;
    const float* p110 = vin + (size_t)(zs1 + ys1 + x0c) * 3;
    const float* p111 = vin + (size_t)(zs1 + ys1 + x1c) * 3;

    // issue all 24 gather loads up front (no control flow between them)
    float a0 = p000[0], a1 = p000[1], a2 = p000[2];
    float b0 = p001[0], b1 = p001[1], b2 = p001[2];
    float c0 = p010[0], c1 = p010[1], c2 = p010[2];
    float d0 = p011[0], d1 = p011[1], d2 = p011[2];
    float e0 = p100[0], e1 = p100[1], e2 = p100[2];
    float f0 = p101[0], f1 = p101[1], f2 = p101[2];
    float g0 = p110[0], g1 = p110[1], g2 = p110[2];
    float h0 = p111[0], h1 = p111[1], h2 = p111[2];

    float w000 = az0 * ay0 * ax0;
    float w001 = az0 * ay0 * ax1;
    float w010 = az0 * ay1 * ax0;
    float w011 = az0 * ay1 * ax1;
    float w100 = az1 * ay0 * ax0;
    float w101 = az1 * ay0 * ax1;
    float w110 = az1 * ay1 * ax0;
    float w111 = az1 * ay1 * ax1;

    float acc0 = w000 * a0;
    float acc1 = w000 * a1;
    float acc2 = w000 * a2;
    acc0 = fmaf(w001, b0, acc0); acc1 = fmaf(w001, b1, acc1); acc2 = fmaf(w001, b2, acc2);
    acc0 = fmaf(w010, c0, acc0); acc1 = fmaf(w010, c1, acc1); acc2 = fmaf(w010, c2, acc2);
    acc0 = fmaf(w011, d0, acc0); acc1 = fmaf(w011, d1, acc1); acc2 = fmaf(w011, d2, acc2);
    acc0 = fmaf(w100, e0, acc0); acc1 = fmaf(w100, e1, acc1); acc2 = fmaf(w100, e2, acc2);
    acc0 = fmaf(w101, f0, acc0); acc1 = fmaf(w101, f1, acc1); acc2 = fmaf(w101, f2, acc2);
    acc0 = fmaf(w110, g0, acc0); acc1 = fmaf(w110, g1, acc1); acc2 = fmaf(w110, g2, acc2);
    acc0 = fmaf(w111, h0, acc0); acc1 = fmaf(w111, h1, acc1); acc2 = fmaf(w111, h2, acc2);

    if (SCALE_SRC) { acc0 *= s; acc1 *= s; acc2 *= s; }

    float r0 = vx + acc0, r1 = vy + acc1, r2 = vz + acc2;

    if (NT_OUT) {
        __builtin_nontemporal_store(r0, &vout[base + 0]);
        __builtin_nontemporal_store(r1, &vout[base + 1]);
        __builtin_nontemporal_store(r2, &vout[base + 2]);
    } else {
        vout[base + 0] = r0;
        vout[base + 1] = r1;
        vout[base + 2] = r2;
    }
}

// fallback init (only used if workspace is too small for two packed buffers)
__global__ __launch_bounds__(256) void gs_init_scale(const float* __restrict__ in,
                                                     float* __restrict__ out,
                                                     int n4, float s) {
    int i = blockIdx.x * blockDim.x + threadIdx.x;
    if (i < n4) {
        float4 v = reinterpret_cast<const float4*>(in)[i];
        v.x *= s; v.y *= s; v.z *= s; v.w *= s;
        reinterpret_cast<float4*>(out)[i] = v;
    }
}

extern "C" void kernel_launch(void* const* d_in, const int* in_sizes, int n_in,
                              void* d_out, int out_size, void* d_ws, size_t ws_size,
                              hipStream_t stream) {
    const float* vel = (const float*)d_in[0];
    float* out = (float*)d_out;

    const float scale = 1.0f / 64.0f;  // 1 / 2^6
    dim3 blk(256);
    dim3 grd(NBLOCK);

    const size_t buf_bytes = (size_t)NVOX * 3 * sizeof(float);  // 49.152 MB

    if (ws_size >= 2 * buf_bytes) {
        float* A = (float*)d_ws;
        float* B = (float*)((char*)d_ws + buf_bytes);

        // step 1 fused with the 1/64 scale: vel -> A
        gs_step<true,  false><<<grd, blk, 0, stream>>>(vel, A, scale);
        // steps 2..5 ping-pong (plain stores: re-read next step)
        gs_step<false, false><<<grd, blk, 0, stream>>>(A, B, scale);
        gs_step<false, false><<<grd, blk, 0, stream>>>(B, A, scale);
        gs_step<false, false><<<grd, blk, 0, stream>>>(A, B, scale);
        gs_step<false, false><<<grd, blk, 0, stream>>>(B, A, scale);
        // step 6: A -> d_out, non-temporal (never re-read)
        gs_step<false, true><<<grd, blk, 0, stream>>>(A, out, scale);
    } else {
        // fallback: init into out, 6 steps out<->ws, even count ends in out
        float* ws = (float*)d_ws;
        const int n4 = NVOX * 3 / 4;
        dim3 grd_init((n4 + 255) / 256);

        gs_init_scale<<<grd_init, blk, 0, stream>>>(vel, out, n4, scale);

        float* src = out;
        float* dst = ws;
        for (int i = 0; i < 6; ++i) {
            gs_step<false, false><<<grd, blk, 0, stream>>>(src, dst, scale);
            float* tmp = src; src = dst; dst = tmp;
        }
    }
}